// Round 4
// baseline (267.425 us; speedup 1.0000x reference)
//
#include <hip/hip_runtime.h>
#include <hip/hip_bf16.h>
#include <cmath>

#define D_MODEL 512
#define D_INNER 1024
#define NHEAD 16
#define HDIM 64
#define NSTATE 16
#define NB 8
#define NT 64
#define NW 16
#define MROWS 8192      // NB*NT*NW
#define PROJ_LD 2176    // padded 2096 -> 17*128
#define NPROJ 2096

typedef __attribute__((ext_vector_type(8))) short short8;
typedef __attribute__((ext_vector_type(4))) float f32x4;
typedef __hip_bfloat16 bf16;

// ---------------- block-wide sum reduction (256 threads = 4 waves) ----------
__device__ __forceinline__ float block_sum(float v, float* sbuf) {
#pragma unroll
  for (int o = 32; o > 0; o >>= 1) v += __shfl_down(v, o, 64);
  int lane = threadIdx.x & 63, wid = threadIdx.x >> 6;
  if (lane == 0) sbuf[wid] = v;
  __syncthreads();
  if (threadIdx.x == 0) {
    float t = 0.f;
    for (int i = 0; i < 4; i++) t += sbuf[i];
    sbuf[0] = t;
  }
  __syncthreads();
  return sbuf[0];
}

// ---------------- LayerNorm over 512, bf16 out ------------------------------
__global__ __launch_bounds__(256) void ln512_bf16_kernel(
    const float* __restrict__ x, const float* __restrict__ w,
    const float* __restrict__ b, bf16* __restrict__ out) {
  __shared__ float s1[8], s2[8];
  int row = blockIdx.x;
  const float* xr = x + (size_t)row * D_MODEL;
  bf16* outr = out + (size_t)row * D_MODEL;
  int c0 = threadIdx.x, c1 = threadIdx.x + 256;
  float v0 = xr[c0], v1 = xr[c1];
  float s  = block_sum(v0 + v1, s1);
  float ss = block_sum(v0 * v0 + v1 * v1, s2);
  float mean = s * (1.f / 512.f);
  float var  = ss * (1.f / 512.f) - mean * mean;
  float inv  = rsqrtf(var + 1e-5f);
  outr[c0] = __float2bfloat16((v0 - mean) * inv * w[c0] + b[c0]);
  outr[c1] = __float2bfloat16((v1 - mean) * inv * w[c1] + b[c1]);
}

// ---------------- weight convert + transpose: fp32 [K][N] -> bf16 [Npad][K] -
__global__ __launch_bounds__(256) void wconv_t_kernel(
    const float* __restrict__ w, bf16* __restrict__ wt,
    int K, int N, int Npad) {
  __shared__ float tile[32][33];
  int n0 = blockIdx.x * 32, k0 = blockIdx.y * 32;
  int tx = threadIdx.x & 31, ty = threadIdx.x >> 5;  // 32 x 8
#pragma unroll
  for (int i = 0; i < 4; i++) {
    int k = k0 + ty + i * 8, n = n0 + tx;
    tile[ty + i * 8][tx] = (k < K && n < N) ? w[(size_t)k * N + n] : 0.f;
  }
  __syncthreads();
#pragma unroll
  for (int i = 0; i < 4; i++) {
    int n = n0 + ty + i * 8, k = k0 + tx;
    if (n < Npad && k < K) wt[(size_t)n * K + k] = __float2bfloat16(tile[tx][ty + i * 8]);
  }
}

// ---------------- bf16 MFMA GEMM: C[M,N] = A[M,K] @ Bt[N,K]^T ---------------
template<int BM, int BN, int WN, int MR, int NR>
__global__ __launch_bounds__(256) void mfma_gemm_kernel(
    const bf16* __restrict__ A, const bf16* __restrict__ Bt,
    const float* __restrict__ bias, int nbias,
    const float* __restrict__ resid,
    float* __restrict__ C, int ldc, int K) {
  constexpr int ROWS = BM + BN;
  constexpr int ISS  = ROWS / 64;
  __shared__ __align__(16) bf16 sAB[ROWS][32];

  int wid = threadIdx.x >> 6, lane = threadIdx.x & 63;
  int row0 = blockIdx.y * BM, col0 = blockIdx.x * BN;
  int wr = (wid / WN) * (MR * 16);
  int wc = (wid % WN) * (NR * 16);

  f32x4 acc[MR][NR];
#pragma unroll
  for (int m = 0; m < MR; m++)
#pragma unroll
    for (int n = 0; n < NR; n++) acc[m][n] = (f32x4){0.f, 0.f, 0.f, 0.f};

  int lr = lane >> 2;
  int lc = (lane & 3) * 8;

  for (int k0 = 0; k0 < K; k0 += 32) {
#pragma unroll
    for (int i = 0; i < ISS; i++) {
      int rb = (wid * ISS + i) * 16;
      int r = rb + lr;
      const bf16* src = (r < BM)
          ? A  + (size_t)(row0 + r) * K + k0 + lc
          : Bt + (size_t)(col0 + (r - BM)) * K + k0 + lc;
      __builtin_amdgcn_global_load_lds(
          (const __attribute__((address_space(1))) void*)src,
          (__attribute__((address_space(3))) void*)&sAB[rb][0], 16, 0, 0);
    }
    asm volatile("s_waitcnt vmcnt(0)" ::: "memory");
    __syncthreads();

    short8 a[MR], b[NR];
    int kk = (lane >> 4) * 8;
#pragma unroll
    for (int m = 0; m < MR; m++)
      a[m] = *(const short8*)&sAB[wr + m * 16 + (lane & 15)][kk];
#pragma unroll
    for (int n = 0; n < NR; n++)
      b[n] = *(const short8*)&sAB[BM + wc + n * 16 + (lane & 15)][kk];
#pragma unroll
    for (int m = 0; m < MR; m++)
#pragma unroll
      for (int n = 0; n < NR; n++)
        acc[m][n] = __builtin_amdgcn_mfma_f32_16x16x32_bf16(a[m], b[n], acc[m][n], 0, 0, 0);
    __syncthreads();
  }

  int crow = row0 + wr + (lane >> 4) * 4;
  int ccol = col0 + wc + (lane & 15);
#pragma unroll
  for (int m = 0; m < MR; m++) {
#pragma unroll
    for (int n = 0; n < NR; n++) {
      int colg = ccol + n * 16;
      float bv = bias ? ((colg < nbias) ? bias[colg] : 0.f) : 0.f;
#pragma unroll
      for (int j = 0; j < 4; j++) {
        int rowg = crow + m * 16 + j;
        float v = acc[m][n][j] + bv;
        if (resid) v += resid[(size_t)rowg * ldc + colg];
        C[(size_t)rowg * ldc + colg] = v;
      }
    }
  }
}

// ---------------- tree scan: LDS state, b128 access, DS-op-minimized --------
// lane = (w, q): w = lane>>2 (tree slot), pl = wid*4 + (lane&3) (p index).
// pl-slices of the state are wave-private -> no per-step barrier.
// State hs[par*324 + pl*20 + n]: strides coprime with bank groups.
__global__ __launch_bounds__(256) void tree_scan_kernel(
    const float* __restrict__ proj, const int* __restrict__ parent,
    const float* __restrict__ A_log, const float* __restrict__ dt_bias,
    const float* __restrict__ Dp, float* __restrict__ y) {
  const int tid = threadIdx.x;
  const int ps = blockIdx.x & 3;
  const int h  = (blockIdx.x >> 2) & 15;
  const int b  = blockIdx.x >> 6;
  const int wid = tid >> 6;
  const int lane = tid & 63;
  const int w  = lane >> 2;
  const int pl = wid * 4 + (lane & 3);

  __shared__ __align__(16) float hs[16 * 324 + 4];   // state [w][pl][16], strided
  __shared__ __align__(16) float Bs[8][16][20];
  __shared__ __align__(16) float Cs[8][16][20];
  __shared__ __align__(16) float X2[8][16][34];      // {dt*x, Dh*x} per pl
  __shared__ __align__(16) float dts[8][16];
  __shared__ __align__(16) float dAt[16][8];
  __shared__ __align__(16) int   part[16][8];

  const float Ah  = -expf(A_log[h]);
  const float dtb = dt_bias[h];
  const float Dh  = Dp[h];
  const int xbase = 1024 + (h << 6) + (ps << 4);

  for (int i = tid; i < 16 * 324 + 4; i += 256) hs[i] = 0.f;

  for (int c = 0; c < 8; c++) {
    const int t0 = c * 8;
    __syncthreads();  // previous chunk compute done / init done
    // phase A: dt, dA, parent (one thread per (t,w))
    if (tid < 128) {
      int t = tid >> 4, wv = tid & 15;
      size_t row = ((size_t)(b * NT + t0 + t)) * NW + wv;
      float dtr = proj[row * PROJ_LD + 2080 + h] + dtb;
      float dtv = (dtr > 20.f) ? dtr : log1pf(expf(dtr));
      dts[t][wv] = dtv;
      dAt[wv][t] = expf(dtv * Ah);
      part[wv][t] = parent[row];
    }
    __syncthreads();
    // phase B: stage B, C, X (512 float4 slots each; thread -> slots tid, tid+256)
#pragma unroll
    for (int r = 0; r < 2; r++) {
      int s = tid + (r << 8);
      int t = s >> 6, wv = (s >> 2) & 15, n4 = (s & 3) << 2;
      size_t row = ((size_t)(b * NT + t0 + t)) * NW + wv;
      const float* pb = proj + row * PROJ_LD;
      float4 bv = *(const float4*)&pb[2048 + n4];
      float4 cv = *(const float4*)&pb[2064 + n4];
      float4 xv = *(const float4*)&pb[xbase + n4];
      *(float4*)&Bs[t][wv][n4] = bv;
      *(float4*)&Cs[t][wv][n4] = cv;
      float dtv = dts[t][wv];
      float4 lo = {xv.x * dtv, xv.x * Dh, xv.y * dtv, xv.y * Dh};
      float4 hi = {xv.z * dtv, xv.z * Dh, xv.w * dtv, xv.w * Dh};
      *(float4*)&X2[t][wv][n4 * 2]     = lo;
      *(float4*)&X2[t][wv][n4 * 2 + 4] = hi;
    }
    __syncthreads();
    // pack dA / parent for this lane's w into registers
    float dAr[8];
    int parr[8];
    *(float4*)&dAr[0] = *(const float4*)&dAt[w][0];
    *(float4*)&dAr[4] = *(const float4*)&dAt[w][4];
    *(int4*)&parr[0]  = *(const int4*)&part[w][0];
    *(int4*)&parr[4]  = *(const int4*)&part[w][4];

#pragma unroll
    for (int tt = 0; tt < 8; tt++) {
      float dA = dAr[tt];
      int par = parr[tt];
      const float* hp = &hs[par * 324 + pl * 20];
      float4 h0 = *(const float4*)&hp[0];
      float4 h1 = *(const float4*)&hp[4];
      float4 h2 = *(const float4*)&hp[8];
      float4 h3 = *(const float4*)&hp[12];
      float2 xx = *(const float2*)&X2[tt][w][pl * 2];
      const float* bp = &Bs[tt][w][0];
      const float* cp = &Cs[tt][w][0];
      float4 b0 = *(const float4*)&bp[0];
      float4 b1 = *(const float4*)&bp[4];
      float4 b2 = *(const float4*)&bp[8];
      float4 b3 = *(const float4*)&bp[12];
      float4 c0 = *(const float4*)&cp[0];
      float4 c1 = *(const float4*)&cp[4];
      float4 c2 = *(const float4*)&cp[8];
      float4 c3 = *(const float4*)&cp[12];
      float dtx = xx.x;
      h0.x = fmaf(dA, h0.x, dtx * b0.x);
      h0.y = fmaf(dA, h0.y, dtx * b0.y);
      h0.z = fmaf(dA, h0.z, dtx * b0.z);
      h0.w = fmaf(dA, h0.w, dtx * b0.w);
      h1.x = fmaf(dA, h1.x, dtx * b1.x);
      h1.y = fmaf(dA, h1.y, dtx * b1.y);
      h1.z = fmaf(dA, h1.z, dtx * b1.z);
      h1.w = fmaf(dA, h1.w, dtx * b1.w);
      h2.x = fmaf(dA, h2.x, dtx * b2.x);
      h2.y = fmaf(dA, h2.y, dtx * b2.y);
      h2.z = fmaf(dA, h2.z, dtx * b2.z);
      h2.w = fmaf(dA, h2.w, dtx * b2.w);
      h3.x = fmaf(dA, h3.x, dtx * b3.x);
      h3.y = fmaf(dA, h3.y, dtx * b3.y);
      h3.z = fmaf(dA, h3.z, dtx * b3.z);
      h3.w = fmaf(dA, h3.w, dtx * b3.w);
      float s0 = h0.x * c0.x + h0.y * c0.y;
      float s1 = h0.z * c0.z + h0.w * c0.w;
      float s2 = h1.x * c1.x + h1.y * c1.y;
      float s3 = h1.z * c1.z + h1.w * c1.w;
      s0 += h2.x * c2.x + h2.y * c2.y;
      s1 += h2.z * c2.z + h2.w * c2.w;
      s2 += h3.x * c3.x + h3.y * c3.y;
      s3 += h3.z * c3.z + h3.w * c3.w;
      float yv = (s0 + s1) + (s2 + s3);
      float* hw = &hs[w * 324 + pl * 20];
      *(float4*)&hw[0]  = h0;
      *(float4*)&hw[4]  = h1;
      *(float4*)&hw[8]  = h2;
      *(float4*)&hw[12] = h3;
      size_t row = ((size_t)(b * NT + t0 + tt)) * NW + w;
      y[row * D_INNER + (h << 6) + (ps << 4) + pl] = yv + xx.y;
    }
  }
}

// ---------------- gated RMSNorm -> bf16 -------------------------------------
__global__ __launch_bounds__(256) void gate_rms_kernel(
    const float* __restrict__ yin, const float* __restrict__ proj,
    const float* __restrict__ norm_w, bf16* __restrict__ out) {
  __shared__ float sbuf[8];
  int row = blockIdx.x;
  const float* yr = yin + (size_t)row * D_INNER;
  const float* zr = proj + (size_t)row * PROJ_LD;
  int c = threadIdx.x * 4;
  float4 y4 = *(const float4*)&yr[c];
  float4 z4 = *(const float4*)&zr[c];
  const float* yp = (const float*)&y4;
  const float* zp = (const float*)&z4;
  float gv[4];
  float ss = 0.f;
#pragma unroll
  for (int j = 0; j < 4; j++) {
    float z = zp[j];
    float t = yp[j] * (z / (1.f + expf(-z)));
    gv[j] = t;
    ss += t * t;
  }
  ss = block_sum(ss, sbuf);
  float scale = rsqrtf(ss * (1.f / 1024.f) + 1e-5f);
  bf16 o4[4];
#pragma unroll
  for (int j = 0; j < 4; j++) o4[j] = __float2bfloat16(gv[j] * scale * norm_w[c + j]);
  *(uint2*)&out[(size_t)row * D_INNER + c] = *(uint2*)o4;
}

// ---------------- FF gate -> bf16 -------------------------------------------
__global__ __launch_bounds__(256) void ffgate_kernel(
    const float* __restrict__ f, bf16* __restrict__ out) {
  size_t i4 = (size_t)blockIdx.x * blockDim.x + threadIdx.x;
  int row = (int)(i4 >> 8);
  int c = ((int)i4 & 255) * 4;
  const float* fr = f + (size_t)row * 2048;
  float4 a = *(const float4*)&fr[c];
  float4 g = *(const float4*)&fr[1024 + c];
  const float* ap = (const float*)&a;
  const float* gp = (const float*)&g;
  bf16 o4[4];
#pragma unroll
  for (int j = 0; j < 4; j++) {
    float z = gp[j];
    o4[j] = __float2bfloat16(ap[j] * (z / (1.f + expf(-z))));
  }
  *(uint2*)&out[(size_t)row * 1024 + c] = *(uint2*)o4;
}

extern "C" void kernel_launch(void* const* d_in, const int* in_sizes, int n_in,
                              void* d_out, int out_size, void* d_ws, size_t ws_size,
                              hipStream_t stream) {
  const float* x       = (const float*)d_in[0];
  const int*   parent  = (const int*)d_in[1];
  const float* ln1_w   = (const float*)d_in[2];
  const float* ln1_b   = (const float*)d_in[3];
  const float* in_w    = (const float*)d_in[4];
  const float* in_b    = (const float*)d_in[5];
  const float* A_log   = (const float*)d_in[6];
  const float* dt_bias = (const float*)d_in[7];
  const float* Dp      = (const float*)d_in[8];
  const float* norm_w  = (const float*)d_in[9];
  const float* out_w   = (const float*)d_in[10];
  const float* out_b   = (const float*)d_in[11];
  const float* ln2_w   = (const float*)d_in[12];
  const float* ln2_b   = (const float*)d_in[13];
  const float* ff1_w   = (const float*)d_in[14];
  const float* ff1_b   = (const float*)d_in[15];
  const float* ff2_w   = (const float*)d_in[16];
  const float* ff2_b   = (const float*)d_in[17];
  float* outp = (float*)d_out;

  char* wp = (char*)d_ws;
  bf16* xnb    = (bf16*)wp;  wp += (size_t)MROWS * D_MODEL * 2;
  bf16* in_wt  = (bf16*)wp;  wp += (size_t)PROJ_LD * D_MODEL * 2;
  bf16* out_wt = (bf16*)wp;  wp += (size_t)D_MODEL * D_INNER * 2;
  bf16* ff1_wt = (bf16*)wp;  wp += (size_t)2048 * D_MODEL * 2;
  bf16* ff2_wt = (bf16*)wp;  wp += (size_t)D_MODEL * D_INNER * 2;
  float* proj  = (float*)wp; wp += (size_t)MROWS * PROJ_LD * 4;  // reused for f
  float* yb    = (float*)wp; wp += (size_t)MROWS * D_INNER * 4;
  bf16* ygb    = (bf16*)wp;  wp += (size_t)MROWS * D_INNER * 2;
  float* xmid  = outp;  // d_out doubles as xmid

  dim3 blk(256);
  wconv_t_kernel<<<dim3(PROJ_LD / 32, D_MODEL / 32), blk, 0, stream>>>(
      in_w, in_wt, D_MODEL, NPROJ, PROJ_LD);
  wconv_t_kernel<<<dim3(D_MODEL / 32, D_INNER / 32), blk, 0, stream>>>(
      out_w, out_wt, D_INNER, D_MODEL, D_MODEL);
  wconv_t_kernel<<<dim3(2048 / 32, D_MODEL / 32), blk, 0, stream>>>(
      ff1_w, ff1_wt, D_MODEL, 2048, 2048);
  wconv_t_kernel<<<dim3(D_MODEL / 32, D_INNER / 32), blk, 0, stream>>>(
      ff2_w, ff2_wt, D_INNER, D_MODEL, D_MODEL);

  // 1) LN1 -> bf16
  ln512_bf16_kernel<<<MROWS, blk, 0, stream>>>(x, ln1_w, ln1_b, xnb);
  // 2) in-proj GEMM -> proj
  mfma_gemm_kernel<128, 128, 2, 4, 4><<<dim3(PROJ_LD / 128, MROWS / 128), blk, 0, stream>>>(
      xnb, in_wt, in_b, NPROJ, nullptr, proj, PROJ_LD, D_MODEL);
  // 3) tree scan -> yb
  tree_scan_kernel<<<NB * NHEAD * 4, blk, 0, stream>>>(proj, parent, A_log,
                                                       dt_bias, Dp, yb);
  // 4) gated RMSNorm -> ygb (bf16)
  gate_rms_kernel<<<MROWS, blk, 0, stream>>>(yb, proj, norm_w, ygb);
  // 5) out-proj GEMM + resid(x) -> xmid
  mfma_gemm_kernel<64, 128, 4, 4, 2><<<dim3(D_MODEL / 128, MROWS / 64), blk, 0, stream>>>(
      ygb, out_wt, out_b, D_MODEL, x, xmid, D_MODEL, D_INNER);
  // 6) LN2 -> xnb (reuse)
  ln512_bf16_kernel<<<MROWS, blk, 0, stream>>>(xmid, ln2_w, ln2_b, xnb);
  // 7) FF1 GEMM -> f (reuse proj buffer, ld 2048)
  mfma_gemm_kernel<128, 128, 2, 4, 4><<<dim3(2048 / 128, MROWS / 128), blk, 0, stream>>>(
      xnb, ff1_wt, ff1_b, 2048, nullptr, proj, 2048, D_MODEL);
  // 8) FF gate -> ygb (reuse)
  ffgate_kernel<<<MROWS, blk, 0, stream>>>(proj, ygb);
  // 9) FF2 GEMM + resid(xmid) -> d_out
  mfma_gemm_kernel<64, 128, 4, 4, 2><<<dim3(D_MODEL / 128, MROWS / 64), blk, 0, stream>>>(
      ygb, ff2_wt, ff2_b, D_MODEL, xmid, outp, D_MODEL, D_INNER);
}

// Round 5
// 253.612 us; speedup vs baseline: 1.0545x; 1.0545x over previous
//
#include <hip/hip_runtime.h>
#include <hip/hip_bf16.h>
#include <cmath>

#define D_MODEL 512
#define D_INNER 1024
#define NHEAD 16
#define HDIM 64
#define NSTATE 16
#define NB 8
#define NT 64
#define NW 16
#define MROWS 8192      // NB*NT*NW
#define PROJ_LD 2176    // padded 2096 -> 17*128
#define NPROJ 2096

typedef __attribute__((ext_vector_type(8))) short short8;
typedef __attribute__((ext_vector_type(4))) float f32x4;
typedef __hip_bfloat16 bf16;

// ---------------- block-wide sum reduction (256 threads = 4 waves) ----------
__device__ __forceinline__ float block_sum(float v, float* sbuf) {
#pragma unroll
  for (int o = 32; o > 0; o >>= 1) v += __shfl_down(v, o, 64);
  int lane = threadIdx.x & 63, wid = threadIdx.x >> 6;
  if (lane == 0) sbuf[wid] = v;
  __syncthreads();
  if (threadIdx.x == 0) {
    float t = 0.f;
    for (int i = 0; i < 4; i++) t += sbuf[i];
    sbuf[0] = t;
  }
  __syncthreads();
  return sbuf[0];
}

// ---------------- LayerNorm over 512, bf16 out ------------------------------
__global__ __launch_bounds__(256) void ln512_bf16_kernel(
    const float* __restrict__ x, const float* __restrict__ w,
    const float* __restrict__ b, bf16* __restrict__ out) {
  __shared__ float s1[8], s2[8];
  int row = blockIdx.x;
  const float* xr = x + (size_t)row * D_MODEL;
  bf16* outr = out + (size_t)row * D_MODEL;
  int c0 = threadIdx.x, c1 = threadIdx.x + 256;
  float v0 = xr[c0], v1 = xr[c1];
  float s  = block_sum(v0 + v1, s1);
  float ss = block_sum(v0 * v0 + v1 * v1, s2);
  float mean = s * (1.f / 512.f);
  float var  = ss * (1.f / 512.f) - mean * mean;
  float inv  = rsqrtf(var + 1e-5f);
  outr[c0] = __float2bfloat16((v0 - mean) * inv * w[c0] + b[c0]);
  outr[c1] = __float2bfloat16((v1 - mean) * inv * w[c1] + b[c1]);
}

// ---------------- weight convert + transpose: fp32 [K][N] -> bf16 [Npad][K] -
__global__ __launch_bounds__(256) void wconv_t_kernel(
    const float* __restrict__ w, bf16* __restrict__ wt,
    int K, int N, int Npad) {
  __shared__ float tile[32][33];
  int n0 = blockIdx.x * 32, k0 = blockIdx.y * 32;
  int tx = threadIdx.x & 31, ty = threadIdx.x >> 5;  // 32 x 8
#pragma unroll
  for (int i = 0; i < 4; i++) {
    int k = k0 + ty + i * 8, n = n0 + tx;
    tile[ty + i * 8][tx] = (k < K && n < N) ? w[(size_t)k * N + n] : 0.f;
  }
  __syncthreads();
#pragma unroll
  for (int i = 0; i < 4; i++) {
    int n = n0 + ty + i * 8, k = k0 + tx;
    if (n < Npad && k < K) wt[(size_t)n * K + k] = __float2bfloat16(tile[tx][ty + i * 8]);
  }
}

// ---------------- fp32-out MFMA GEMM (out-proj / ff2) -----------------------
template<int BM, int BN, int WN, int MR, int NR>
__global__ __launch_bounds__(256) void mfma_gemm_kernel(
    const bf16* __restrict__ A, const bf16* __restrict__ Bt,
    const float* __restrict__ bias, int nbias,
    const float* __restrict__ resid,
    float* __restrict__ C, int ldc, int K) {
  constexpr int ROWS = BM + BN;
  constexpr int ISS  = ROWS / 64;
  __shared__ __align__(16) bf16 sAB[ROWS][32];

  int wid = threadIdx.x >> 6, lane = threadIdx.x & 63;
  int row0 = blockIdx.y * BM, col0 = blockIdx.x * BN;
  int wr = (wid / WN) * (MR * 16);
  int wc = (wid % WN) * (NR * 16);

  f32x4 acc[MR][NR];
#pragma unroll
  for (int m = 0; m < MR; m++)
#pragma unroll
    for (int n = 0; n < NR; n++) acc[m][n] = (f32x4){0.f, 0.f, 0.f, 0.f};

  int lr = lane >> 2;
  int lc = (lane & 3) * 8;

  for (int k0 = 0; k0 < K; k0 += 32) {
#pragma unroll
    for (int i = 0; i < ISS; i++) {
      int rb = (wid * ISS + i) * 16;
      int r = rb + lr;
      const bf16* src = (r < BM)
          ? A  + (size_t)(row0 + r) * K + k0 + lc
          : Bt + (size_t)(col0 + (r - BM)) * K + k0 + lc;
      __builtin_amdgcn_global_load_lds(
          (const __attribute__((address_space(1))) void*)src,
          (__attribute__((address_space(3))) void*)&sAB[rb][0], 16, 0, 0);
    }
    asm volatile("s_waitcnt vmcnt(0)" ::: "memory");
    __syncthreads();

    short8 a[MR], b[NR];
    int kk = (lane >> 4) * 8;
#pragma unroll
    for (int m = 0; m < MR; m++)
      a[m] = *(const short8*)&sAB[wr + m * 16 + (lane & 15)][kk];
#pragma unroll
    for (int n = 0; n < NR; n++)
      b[n] = *(const short8*)&sAB[BM + wc + n * 16 + (lane & 15)][kk];
#pragma unroll
    for (int m = 0; m < MR; m++)
#pragma unroll
      for (int n = 0; n < NR; n++)
        acc[m][n] = __builtin_amdgcn_mfma_f32_16x16x32_bf16(a[m], b[n], acc[m][n], 0, 0, 0);
    __syncthreads();
  }

  int crow = row0 + wr + (lane >> 4) * 4;
  int ccol = col0 + wc + (lane & 15);
#pragma unroll
  for (int m = 0; m < MR; m++) {
#pragma unroll
    for (int n = 0; n < NR; n++) {
      int colg = ccol + n * 16;
      float bv = bias ? ((colg < nbias) ? bias[colg] : 0.f) : 0.f;
#pragma unroll
      for (int j = 0; j < 4; j++) {
        int rowg = crow + m * 16 + j;
        float v = acc[m][n][j] + bv;
        if (resid) v += resid[(size_t)rowg * ldc + colg];
        C[(size_t)rowg * ldc + colg] = v;
      }
    }
  }
}

// ---------------- in-proj GEMM: bf16 out + fp32 aux for cols>=2048 ----------
__global__ __launch_bounds__(256) void inproj_gemm_kernel(
    const bf16* __restrict__ A, const bf16* __restrict__ Bt,
    const float* __restrict__ bias,
    bf16* __restrict__ Cb, float* __restrict__ aux, int K) {
  constexpr int BM = 128, BN = 128, ROWS = 256, ISS = 4;
  __shared__ __align__(16) bf16 sAB[ROWS][32];

  int wid = threadIdx.x >> 6, lane = threadIdx.x & 63;
  int row0 = blockIdx.y * BM, col0 = blockIdx.x * BN;
  int wr = (wid >> 1) * 64;
  int wc = (wid & 1) * 64;

  f32x4 acc[4][4];
#pragma unroll
  for (int m = 0; m < 4; m++)
#pragma unroll
    for (int n = 0; n < 4; n++) acc[m][n] = (f32x4){0.f, 0.f, 0.f, 0.f};

  int lr = lane >> 2;
  int lc = (lane & 3) * 8;

  for (int k0 = 0; k0 < K; k0 += 32) {
#pragma unroll
    for (int i = 0; i < ISS; i++) {
      int rb = (wid * ISS + i) * 16;
      int r = rb + lr;
      const bf16* src = (r < BM)
          ? A  + (size_t)(row0 + r) * K + k0 + lc
          : Bt + (size_t)(col0 + (r - BM)) * K + k0 + lc;
      __builtin_amdgcn_global_load_lds(
          (const __attribute__((address_space(1))) void*)src,
          (__attribute__((address_space(3))) void*)&sAB[rb][0], 16, 0, 0);
    }
    asm volatile("s_waitcnt vmcnt(0)" ::: "memory");
    __syncthreads();

    short8 a[4], b[4];
    int kk = (lane >> 4) * 8;
#pragma unroll
    for (int m = 0; m < 4; m++)
      a[m] = *(const short8*)&sAB[wr + m * 16 + (lane & 15)][kk];
#pragma unroll
    for (int n = 0; n < 4; n++)
      b[n] = *(const short8*)&sAB[BM + wc + n * 16 + (lane & 15)][kk];
#pragma unroll
    for (int m = 0; m < 4; m++)
#pragma unroll
      for (int n = 0; n < 4; n++)
        acc[m][n] = __builtin_amdgcn_mfma_f32_16x16x32_bf16(a[m], b[n], acc[m][n], 0, 0, 0);
    __syncthreads();
  }

  int crow = row0 + wr + (lane >> 4) * 4;
  int ccol = col0 + wc + (lane & 15);
#pragma unroll
  for (int m = 0; m < 4; m++) {
#pragma unroll
    for (int n = 0; n < 4; n++) {
      int colg = ccol + n * 16;
      float bv = (colg < NPROJ) ? bias[colg] : 0.f;
#pragma unroll
      for (int j = 0; j < 4; j++) {
        int rowg = crow + m * 16 + j;
        float v = acc[m][n][j] + bv;
        Cb[(size_t)rowg * PROJ_LD + colg] = __float2bfloat16(v);
        if (colg >= 2048 && colg < 2112)
          aux[(size_t)rowg * 64 + (colg - 2048)] = v;
      }
    }
  }
}

// ---------------- FF1 GEMM fused with SiLU gate -> bf16 ---------------------
// Each block computes cols [c0,c0+128) of f1 AND [1024+c0,...) of g,
// then writes f1*silu(g) bf16. Grid: (8, 64).
__global__ __launch_bounds__(256) void ff1_fused_kernel(
    const bf16* __restrict__ A, const bf16* __restrict__ Bt,
    const float* __restrict__ bias, bf16* __restrict__ out, int K) {
  constexpr int BM = 128, ROWS = 384, ISS = 6;
  __shared__ __align__(16) bf16 sAB[ROWS][32];

  int wid = threadIdx.x >> 6, lane = threadIdx.x & 63;
  int row0 = blockIdx.y * BM, col0 = blockIdx.x * 128;
  int wr = (wid >> 1) * 64;
  int wc = (wid & 1) * 64;

  f32x4 acc1[4][4], acc2[4][4];
#pragma unroll
  for (int m = 0; m < 4; m++)
#pragma unroll
    for (int n = 0; n < 4; n++) {
      acc1[m][n] = (f32x4){0.f, 0.f, 0.f, 0.f};
      acc2[m][n] = (f32x4){0.f, 0.f, 0.f, 0.f};
    }

  int lr = lane >> 2;
  int lc = (lane & 3) * 8;

  for (int k0 = 0; k0 < K; k0 += 32) {
#pragma unroll
    for (int i = 0; i < ISS; i++) {
      int rb = (wid * ISS + i) * 16;
      int r = rb + lr;
      const bf16* src;
      if (r < BM)            src = A  + (size_t)(row0 + r) * K + k0 + lc;
      else if (r < 256)      src = Bt + (size_t)(col0 + (r - 128)) * K + k0 + lc;
      else                   src = Bt + (size_t)(1024 + col0 + (r - 256)) * K + k0 + lc;
      __builtin_amdgcn_global_load_lds(
          (const __attribute__((address_space(1))) void*)src,
          (__attribute__((address_space(3))) void*)&sAB[rb][0], 16, 0, 0);
    }
    asm volatile("s_waitcnt vmcnt(0)" ::: "memory");
    __syncthreads();

    short8 a[4], b1[4], b2[4];
    int kk = (lane >> 4) * 8;
#pragma unroll
    for (int m = 0; m < 4; m++)
      a[m] = *(const short8*)&sAB[wr + m * 16 + (lane & 15)][kk];
#pragma unroll
    for (int n = 0; n < 4; n++) {
      b1[n] = *(const short8*)&sAB[128 + wc + n * 16 + (lane & 15)][kk];
      b2[n] = *(const short8*)&sAB[256 + wc + n * 16 + (lane & 15)][kk];
    }
#pragma unroll
    for (int m = 0; m < 4; m++)
#pragma unroll
      for (int n = 0; n < 4; n++) {
        acc1[m][n] = __builtin_amdgcn_mfma_f32_16x16x32_bf16(a[m], b1[n], acc1[m][n], 0, 0, 0);
        acc2[m][n] = __builtin_amdgcn_mfma_f32_16x16x32_bf16(a[m], b2[n], acc2[m][n], 0, 0, 0);
      }
    __syncthreads();
  }

  int crow = row0 + wr + (lane >> 4) * 4;
  int ccol = col0 + wc + (lane & 15);
#pragma unroll
  for (int m = 0; m < 4; m++) {
#pragma unroll
    for (int n = 0; n < 4; n++) {
      int colg = ccol + n * 16;
      float bv1 = bias[colg];
      float bv2 = bias[1024 + colg];
#pragma unroll
      for (int j = 0; j < 4; j++) {
        int rowg = crow + m * 16 + j;
        float f1 = acc1[m][n][j] + bv1;
        float g  = acc2[m][n][j] + bv2;
        float sg = g / (1.f + expf(-g));
        out[(size_t)rowg * 1024 + colg] = __float2bfloat16(f1 * sg);
      }
    }
  }
}

// ---------------- tree scan: reg state + bpermute gather, b128 B/C ----------
// lane = w*4+q (w = lane>>2); pl = wid*4+q. State h[16] in VGPRs.
// Gather h[par][pl][:] from lane par*4+q via ds_bpermute (same wave).
__global__ __launch_bounds__(256) void tree_scan_kernel(
    const bf16* __restrict__ xb, const float* __restrict__ aux,
    const int* __restrict__ parent,
    const float* __restrict__ A_log, const float* __restrict__ dt_bias,
    const float* __restrict__ Dp, bf16* __restrict__ y) {
  const int tid = threadIdx.x;
  const int ps = blockIdx.x & 3;
  const int h  = (blockIdx.x >> 2) & 15;
  const int b  = blockIdx.x >> 6;
  const int wid = tid >> 6;
  const int lane = tid & 63;
  const int w = lane >> 2;
  const int q = lane & 3;
  const int pl = wid * 4 + q;

  __shared__ __align__(16) float Bs[8][16][20];   // stride-20 rows (80B, 16B-aligned)
  __shared__ __align__(16) float Cs[8][16][20];
  __shared__ __align__(16) float dAs[16][8];      // [w][t]
  __shared__ __align__(16) float dtss[16][8];
  __shared__ __align__(16) int   pars[16][8];

  const float Ah  = -expf(A_log[h]);
  const float dtb = dt_bias[h];
  const float Dh  = Dp[h];
  const int xcol = 1024 + (h << 6) + (ps << 4) + pl;
  const int ycol = (h << 6) + (ps << 4) + pl;

  float hst[16];
#pragma unroll
  for (int n = 0; n < 16; n++) hst[n] = 0.f;

  for (int c = 0; c < 8; c++) {
    const int t0 = c * 8;
    __syncthreads();  // previous chunk's compute done
    // x prefetch for this lane's (w, pl): 8 bf16 global loads
    float xv[8];
#pragma unroll
    for (int tt = 0; tt < 8; tt++) {
      size_t row = ((size_t)(b * NT + t0 + tt)) * NW + w;
      xv[tt] = __bfloat162float(xb[row * PROJ_LD + xcol]);
    }
    // stage dt / dA / parent (transposed [w][t])
    if (tid < 128) {
      int t = tid >> 4, wv = tid & 15;
      size_t row = ((size_t)(b * NT + t0 + t)) * NW + wv;
      float dtr = aux[row * 64 + 32 + h] + dtb;
      float dtv = (dtr > 20.f) ? dtr : log1pf(expf(dtr));
      dtss[wv][t] = dtv;
      dAs[wv][t]  = expf(dtv * Ah);
      pars[wv][t] = parent[row];
    }
    // stage B/C: 1024 float4 slots over 4 rounds
#pragma unroll
    for (int r = 0; r < 4; r++) {
      int idx = tid + (r << 8);
      int t = idx >> 7, rem = idx & 127;
      int wv = rem >> 3, c4 = rem & 7;
      size_t row = ((size_t)(b * NT + t0 + t)) * NW + wv;
      float4 v = *(const float4*)&aux[row * 64 + c4 * 4];
      if (c4 < 4) *(float4*)&Bs[t][wv][c4 * 4] = v;
      else        *(float4*)&Cs[t][wv][(c4 - 4) * 4] = v;
    }
    __syncthreads();
    // reg-pack per-lane (w) params
    float dAr[8], dtr8[8];
    int parr[8];
    *(float4*)&dAr[0]  = *(const float4*)&dAs[w][0];
    *(float4*)&dAr[4]  = *(const float4*)&dAs[w][4];
    *(float4*)&dtr8[0] = *(const float4*)&dtss[w][0];
    *(float4*)&dtr8[4] = *(const float4*)&dtss[w][4];
    *(int4*)&parr[0]   = *(const int4*)&pars[w][0];
    *(int4*)&parr[4]   = *(const int4*)&pars[w][4];

#pragma unroll
    for (int tt = 0; tt < 8; tt++) {
      float dA  = dAr[tt];
      float dtx = dtr8[tt] * xv[tt];
      int   par = parr[tt];
      int gidx = (((par << 2) | q) << 2);
      // gather parent state (16 bpermutes, fp32)
      float hp[16];
#pragma unroll
      for (int n = 0; n < 16; n++)
        hp[n] = __int_as_float(__builtin_amdgcn_ds_bpermute(gidx, __float_as_int(hst[n])));
      // broadcast B/C rows (b128, same addr within 4-lane group)
      float4 b0 = *(const float4*)&Bs[tt][w][0];
      float4 b1 = *(const float4*)&Bs[tt][w][4];
      float4 b2 = *(const float4*)&Bs[tt][w][8];
      float4 b3 = *(const float4*)&Bs[tt][w][12];
      float4 c0 = *(const float4*)&Cs[tt][w][0];
      float4 c1 = *(const float4*)&Cs[tt][w][4];
      float4 c2 = *(const float4*)&Cs[tt][w][8];
      float4 c3 = *(const float4*)&Cs[tt][w][12];
      const float* bp = (const float*)&b0;  // b0..b3 contiguous? no — use per-vec
      float yv = 0.f;
      // n = 0..3
      hst[0] = fmaf(dA, hp[0], dtx * b0.x);  yv = fmaf(hst[0], c0.x, yv);
      hst[1] = fmaf(dA, hp[1], dtx * b0.y);  yv = fmaf(hst[1], c0.y, yv);
      hst[2] = fmaf(dA, hp[2], dtx * b0.z);  yv = fmaf(hst[2], c0.z, yv);
      hst[3] = fmaf(dA, hp[3], dtx * b0.w);  yv = fmaf(hst[3], c0.w, yv);
      hst[4] = fmaf(dA, hp[4], dtx * b1.x);  yv = fmaf(hst[4], c1.x, yv);
      hst[5] = fmaf(dA, hp[5], dtx * b1.y);  yv = fmaf(hst[5], c1.y, yv);
      hst[6] = fmaf(dA, hp[6], dtx * b1.z);  yv = fmaf(hst[6], c1.z, yv);
      hst[7] = fmaf(dA, hp[7], dtx * b1.w);  yv = fmaf(hst[7], c1.w, yv);
      hst[8] = fmaf(dA, hp[8], dtx * b2.x);  yv = fmaf(hst[8], c2.x, yv);
      hst[9] = fmaf(dA, hp[9], dtx * b2.y);  yv = fmaf(hst[9], c2.y, yv);
      hst[10] = fmaf(dA, hp[10], dtx * b2.z); yv = fmaf(hst[10], c2.z, yv);
      hst[11] = fmaf(dA, hp[11], dtx * b2.w); yv = fmaf(hst[11], c2.w, yv);
      hst[12] = fmaf(dA, hp[12], dtx * b3.x); yv = fmaf(hst[12], c3.x, yv);
      hst[13] = fmaf(dA, hp[13], dtx * b3.y); yv = fmaf(hst[13], c3.y, yv);
      hst[14] = fmaf(dA, hp[14], dtx * b3.z); yv = fmaf(hst[14], c3.z, yv);
      hst[15] = fmaf(dA, hp[15], dtx * b3.w); yv = fmaf(hst[15], c3.w, yv);
      (void)bp;
      size_t row = ((size_t)(b * NT + t0 + tt)) * NW + w;
      y[row * D_INNER + ycol] = __float2bfloat16(fmaf(Dh, xv[tt], yv));
    }
  }
}

// ---------------- gated RMSNorm (bf16 in/out) -------------------------------
__global__ __launch_bounds__(256) void gate_rms_kernel(
    const bf16* __restrict__ yin, const bf16* __restrict__ projb,
    const float* __restrict__ norm_w, bf16* __restrict__ out) {
  __shared__ float sbuf[8];
  int row = blockIdx.x;
  const bf16* yr = yin + (size_t)row * D_INNER;
  const bf16* zr = projb + (size_t)row * PROJ_LD;  // z = cols [0,1024)
  int c = threadIdx.x * 4;
  bf16 y4[4], z4[4];
  *(uint2*)y4 = *(const uint2*)&yr[c];
  *(uint2*)z4 = *(const uint2*)&zr[c];
  float gv[4];
  float ss = 0.f;
#pragma unroll
  for (int j = 0; j < 4; j++) {
    float z = __bfloat162float(z4[j]);
    float t = __bfloat162float(y4[j]) * (z / (1.f + expf(-z)));
    gv[j] = t;
    ss += t * t;
  }
  ss = block_sum(ss, sbuf);
  float scale = rsqrtf(ss * (1.f / 1024.f) + 1e-5f);
  bf16 o4[4];
#pragma unroll
  for (int j = 0; j < 4; j++) o4[j] = __float2bfloat16(gv[j] * scale * norm_w[c + j]);
  *(uint2*)&out[(size_t)row * D_INNER + c] = *(uint2*)o4;
}

extern "C" void kernel_launch(void* const* d_in, const int* in_sizes, int n_in,
                              void* d_out, int out_size, void* d_ws, size_t ws_size,
                              hipStream_t stream) {
  const float* x       = (const float*)d_in[0];
  const int*   parent  = (const int*)d_in[1];
  const float* ln1_w   = (const float*)d_in[2];
  const float* ln1_b   = (const float*)d_in[3];
  const float* in_w    = (const float*)d_in[4];
  const float* in_b    = (const float*)d_in[5];
  const float* A_log   = (const float*)d_in[6];
  const float* dt_bias = (const float*)d_in[7];
  const float* Dp      = (const float*)d_in[8];
  const float* norm_w  = (const float*)d_in[9];
  const float* out_w   = (const float*)d_in[10];
  const float* out_b   = (const float*)d_in[11];
  const float* ln2_w   = (const float*)d_in[12];
  const float* ln2_b   = (const float*)d_in[13];
  const float* ff1_w   = (const float*)d_in[14];
  const float* ff1_b   = (const float*)d_in[15];
  const float* ff2_w   = (const float*)d_in[16];
  const float* ff2_b   = (const float*)d_in[17];
  float* outp = (float*)d_out;

  char* wp = (char*)d_ws;
  bf16* xnb    = (bf16*)wp;  wp += (size_t)MROWS * D_MODEL * 2;
  bf16* in_wt  = (bf16*)wp;  wp += (size_t)PROJ_LD * D_MODEL * 2;
  bf16* out_wt = (bf16*)wp;  wp += (size_t)D_MODEL * D_INNER * 2;
  bf16* ff1_wt = (bf16*)wp;  wp += (size_t)2048 * D_MODEL * 2;
  bf16* ff2_wt = (bf16*)wp;  wp += (size_t)D_MODEL * D_INNER * 2;
  bf16* projb  = (bf16*)wp;  wp += (size_t)MROWS * PROJ_LD * 2;
  float* aux   = (float*)wp; wp += (size_t)MROWS * 64 * 4;
  bf16* yb     = (bf16*)wp;  wp += (size_t)MROWS * D_INNER * 2;
  bf16* ygb    = (bf16*)wp;  wp += (size_t)MROWS * D_INNER * 2;
  float* xmid  = outp;  // d_out doubles as xmid

  dim3 blk(256);
  wconv_t_kernel<<<dim3(PROJ_LD / 32, D_MODEL / 32), blk, 0, stream>>>(
      in_w, in_wt, D_MODEL, NPROJ, PROJ_LD);
  wconv_t_kernel<<<dim3(D_MODEL / 32, D_INNER / 32), blk, 0, stream>>>(
      out_w, out_wt, D_INNER, D_MODEL, D_MODEL);
  wconv_t_kernel<<<dim3(2048 / 32, D_MODEL / 32), blk, 0, stream>>>(
      ff1_w, ff1_wt, D_MODEL, 2048, 2048);
  wconv_t_kernel<<<dim3(D_MODEL / 32, D_INNER / 32), blk, 0, stream>>>(
      ff2_w, ff2_wt, D_INNER, D_MODEL, D_MODEL);

  // 1) LN1 -> bf16
  ln512_bf16_kernel<<<MROWS, blk, 0, stream>>>(x, ln1_w, ln1_b, xnb);
  // 2) in-proj GEMM -> projb (bf16) + aux (fp32 B/C/dt)
  inproj_gemm_kernel<<<dim3(PROJ_LD / 128, MROWS / 128), blk, 0, stream>>>(
      xnb, in_wt, in_b, projb, aux, D_MODEL);
  // 3) tree scan -> yb (bf16)
  tree_scan_kernel<<<NB * NHEAD * 4, blk, 0, stream>>>(projb, aux, parent,
                                                       A_log, dt_bias, Dp, yb);
  // 4) gated RMSNorm -> ygb (bf16)
  gate_rms_kernel<<<MROWS, blk, 0, stream>>>(yb, projb, norm_w, ygb);
  // 5) out-proj GEMM + resid(x) -> xmid (fp32)
  mfma_gemm_kernel<64, 128, 4, 4, 2><<<dim3(D_MODEL / 128, MROWS / 64), blk, 0, stream>>>(
      ygb, out_wt, out_b, D_MODEL, x, xmid, D_MODEL, D_INNER);
  // 6) LN2 -> xnb
  ln512_bf16_kernel<<<MROWS, blk, 0, stream>>>(xmid, ln2_w, ln2_b, xnb);
  // 7) FF1 GEMM + SiLU gate fused -> ygb (bf16, reuse)
  ff1_fused_kernel<<<dim3(8, MROWS / 128), blk, 0, stream>>>(
      xnb, ff1_wt, ff1_b, ygb, D_MODEL);
  // 8) FF2 GEMM + resid(xmid) -> d_out
  mfma_gemm_kernel<64, 128, 4, 4, 2><<<dim3(D_MODEL / 128, MROWS / 64), blk, 0, stream>>>(
      ygb, ff2_wt, ff2_b, D_MODEL, xmid, outp, D_MODEL, D_INNER);
}

// Round 6
// 218.177 us; speedup vs baseline: 1.2257x; 1.1624x over previous
//
#include <hip/hip_runtime.h>
#include <hip/hip_bf16.h>
#include <cmath>

#define D_MODEL 512
#define D_INNER 1024
#define NHEAD 16
#define HDIM 64
#define NSTATE 16
#define NB 8
#define NT 64
#define NW 16
#define MROWS 8192      // NB*NT*NW
#define PROJ_LD 2176    // padded 2096 -> 17*128
#define NPROJ 2096

typedef __attribute__((ext_vector_type(8))) short short8;
typedef __attribute__((ext_vector_type(4))) float f32x4;
typedef __hip_bfloat16 bf16;
typedef unsigned int u32;

__device__ __forceinline__ u32 fbits(float f) { return __float_as_uint(f); }
__device__ __forceinline__ float ubits(u32 u) { return __uint_as_float(u); }
// pack two fp32 into one u32 of bf16 (truncation): low16 = a, high16 = b
__device__ __forceinline__ u32 pack_bf(float a, float b) {
  return (fbits(b) & 0xffff0000u) | (fbits(a) >> 16);
}

// ---------------- block-wide sum reduction (256 threads = 4 waves) ----------
__device__ __forceinline__ float block_sum(float v, float* sbuf) {
#pragma unroll
  for (int o = 32; o > 0; o >>= 1) v += __shfl_down(v, o, 64);
  int lane = threadIdx.x & 63, wid = threadIdx.x >> 6;
  if (lane == 0) sbuf[wid] = v;
  __syncthreads();
  if (threadIdx.x == 0) {
    float t = 0.f;
    for (int i = 0; i < 4; i++) t += sbuf[i];
    sbuf[0] = t;
  }
  __syncthreads();
  return sbuf[0];
}

// ---------------- LayerNorm over 512, bf16 out ------------------------------
__global__ __launch_bounds__(256) void ln512_bf16_kernel(
    const float* __restrict__ x, const float* __restrict__ w,
    const float* __restrict__ b, bf16* __restrict__ out) {
  __shared__ float s1[8], s2[8];
  int row = blockIdx.x;
  const float* xr = x + (size_t)row * D_MODEL;
  bf16* outr = out + (size_t)row * D_MODEL;
  int c0 = threadIdx.x, c1 = threadIdx.x + 256;
  float v0 = xr[c0], v1 = xr[c1];
  float s  = block_sum(v0 + v1, s1);
  float ss = block_sum(v0 * v0 + v1 * v1, s2);
  float mean = s * (1.f / 512.f);
  float var  = ss * (1.f / 512.f) - mean * mean;
  float inv  = rsqrtf(var + 1e-5f);
  outr[c0] = __float2bfloat16((v0 - mean) * inv * w[c0] + b[c0]);
  outr[c1] = __float2bfloat16((v1 - mean) * inv * w[c1] + b[c1]);
}

// ---------------- weight convert + transpose: fp32 [K][N] -> bf16 [Npad][K] -
__global__ __launch_bounds__(256) void wconv_t_kernel(
    const float* __restrict__ w, bf16* __restrict__ wt,
    int K, int N, int Npad) {
  __shared__ float tile[32][33];
  int n0 = blockIdx.x * 32, k0 = blockIdx.y * 32;
  int tx = threadIdx.x & 31, ty = threadIdx.x >> 5;  // 32 x 8
#pragma unroll
  for (int i = 0; i < 4; i++) {
    int k = k0 + ty + i * 8, n = n0 + tx;
    tile[ty + i * 8][tx] = (k < K && n < N) ? w[(size_t)k * N + n] : 0.f;
  }
  __syncthreads();
#pragma unroll
  for (int i = 0; i < 4; i++) {
    int n = n0 + ty + i * 8, k = k0 + tx;
    if (n < Npad && k < K) wt[(size_t)n * K + k] = __float2bfloat16(tile[tx][ty + i * 8]);
  }
}

// ---------------- fp32-out MFMA GEMM, 2-phase double-buffered ---------------
template<int BM, int BN, int WN, int MR, int NR>
__global__ __launch_bounds__(256) void mfma_gemm_kernel(
    const bf16* __restrict__ A, const bf16* __restrict__ Bt,
    const float* __restrict__ bias, int nbias,
    const float* __restrict__ resid,
    float* __restrict__ C, int ldc, int K) {
  constexpr int ROWS = BM + BN;
  constexpr int ISS  = ROWS / 64;
  __shared__ __align__(16) bf16 sAB[2][ROWS][32];

  int wid = threadIdx.x >> 6, lane = threadIdx.x & 63;
  int row0 = blockIdx.y * BM, col0 = blockIdx.x * BN;
  int wr = (wid / WN) * (MR * 16);
  int wc = (wid % WN) * (NR * 16);
  int lr = lane >> 2;
  int lc = (lane & 3) * 8;

  f32x4 acc[MR][NR];
#pragma unroll
  for (int m = 0; m < MR; m++)
#pragma unroll
    for (int n = 0; n < NR; n++) acc[m][n] = (f32x4){0.f, 0.f, 0.f, 0.f};

  auto stage = [&](int buf, int k0) {
#pragma unroll
    for (int i = 0; i < ISS; i++) {
      int rb = (wid * ISS + i) * 16;
      int r = rb + lr;
      const bf16* src = (r < BM)
          ? A  + (size_t)(row0 + r) * K + k0 + lc
          : Bt + (size_t)(col0 + (r - BM)) * K + k0 + lc;
      __builtin_amdgcn_global_load_lds(
          (const __attribute__((address_space(1))) void*)src,
          (__attribute__((address_space(3))) void*)&sAB[buf][rb][0], 16, 0, 0);
    }
  };

  stage(0, 0);
  asm volatile("s_waitcnt vmcnt(0)" ::: "memory");
  __syncthreads();

  int cur = 0;
  for (int k0 = 0; k0 < K; k0 += 32, cur ^= 1) {
    if (k0 + 32 < K) stage(cur ^ 1, k0 + 32);
    short8 a[MR], b[NR];
    int kk = (lane >> 4) * 8;
#pragma unroll
    for (int m = 0; m < MR; m++)
      a[m] = *(const short8*)&sAB[cur][wr + m * 16 + (lane & 15)][kk];
#pragma unroll
    for (int n = 0; n < NR; n++)
      b[n] = *(const short8*)&sAB[cur][BM + wc + n * 16 + (lane & 15)][kk];
#pragma unroll
    for (int m = 0; m < MR; m++)
#pragma unroll
      for (int n = 0; n < NR; n++)
        acc[m][n] = __builtin_amdgcn_mfma_f32_16x16x32_bf16(a[m], b[n], acc[m][n], 0, 0, 0);
    asm volatile("s_waitcnt vmcnt(0)" ::: "memory");
    __syncthreads();
  }

  int crow = row0 + wr + (lane >> 4) * 4;
  int ccol = col0 + wc + (lane & 15);
#pragma unroll
  for (int m = 0; m < MR; m++) {
#pragma unroll
    for (int n = 0; n < NR; n++) {
      int colg = ccol + n * 16;
      float bv = bias ? ((colg < nbias) ? bias[colg] : 0.f) : 0.f;
#pragma unroll
      for (int j = 0; j < 4; j++) {
        int rowg = crow + m * 16 + j;
        float v = acc[m][n][j] + bv;
        if (resid) v += resid[(size_t)rowg * ldc + colg];
        C[(size_t)rowg * ldc + colg] = v;
      }
    }
  }
}

// ---------------- in-proj GEMM (2-phase): bf16 out + fp32 aux ---------------
__global__ __launch_bounds__(256) void inproj_gemm_kernel(
    const bf16* __restrict__ A, const bf16* __restrict__ Bt,
    const float* __restrict__ bias,
    bf16* __restrict__ Cb, float* __restrict__ aux, int K) {
  constexpr int BM = 128, ROWS = 256, ISS = 4;
  __shared__ __align__(16) bf16 sAB[2][ROWS][32];

  int wid = threadIdx.x >> 6, lane = threadIdx.x & 63;
  int row0 = blockIdx.y * BM, col0 = blockIdx.x * 128;
  int wr = (wid >> 1) * 64;
  int wc = (wid & 1) * 64;
  int lr = lane >> 2;
  int lc = (lane & 3) * 8;

  f32x4 acc[4][4];
#pragma unroll
  for (int m = 0; m < 4; m++)
#pragma unroll
    for (int n = 0; n < 4; n++) acc[m][n] = (f32x4){0.f, 0.f, 0.f, 0.f};

  auto stage = [&](int buf, int k0) {
#pragma unroll
    for (int i = 0; i < ISS; i++) {
      int rb = (wid * ISS + i) * 16;
      int r = rb + lr;
      const bf16* src = (r < BM)
          ? A  + (size_t)(row0 + r) * K + k0 + lc
          : Bt + (size_t)(col0 + (r - BM)) * K + k0 + lc;
      __builtin_amdgcn_global_load_lds(
          (const __attribute__((address_space(1))) void*)src,
          (__attribute__((address_space(3))) void*)&sAB[buf][rb][0], 16, 0, 0);
    }
  };

  stage(0, 0);
  asm volatile("s_waitcnt vmcnt(0)" ::: "memory");
  __syncthreads();

  int cur = 0;
  for (int k0 = 0; k0 < K; k0 += 32, cur ^= 1) {
    if (k0 + 32 < K) stage(cur ^ 1, k0 + 32);
    short8 a[4], b[4];
    int kk = (lane >> 4) * 8;
#pragma unroll
    for (int m = 0; m < 4; m++)
      a[m] = *(const short8*)&sAB[cur][wr + m * 16 + (lane & 15)][kk];
#pragma unroll
    for (int n = 0; n < 4; n++)
      b[n] = *(const short8*)&sAB[cur][BM + wc + n * 16 + (lane & 15)][kk];
#pragma unroll
    for (int m = 0; m < 4; m++)
#pragma unroll
      for (int n = 0; n < 4; n++)
        acc[m][n] = __builtin_amdgcn_mfma_f32_16x16x32_bf16(a[m], b[n], acc[m][n], 0, 0, 0);
    asm volatile("s_waitcnt vmcnt(0)" ::: "memory");
    __syncthreads();
  }

  int crow = row0 + wr + (lane >> 4) * 4;
  int ccol = col0 + wc + (lane & 15);
#pragma unroll
  for (int m = 0; m < 4; m++) {
#pragma unroll
    for (int n = 0; n < 4; n++) {
      int colg = ccol + n * 16;
      float bv = (colg < NPROJ) ? bias[colg] : 0.f;
#pragma unroll
      for (int j = 0; j < 4; j++) {
        int rowg = crow + m * 16 + j;
        float v = acc[m][n][j] + bv;
        Cb[(size_t)rowg * PROJ_LD + colg] = __float2bfloat16(v);
        if (colg >= 2048 && colg < 2112)
          aux[(size_t)rowg * 64 + (colg - 2048)] = v;
      }
    }
  }
}

// ---------------- FF1 GEMM fused with SiLU gate (2-phase) -> bf16 -----------
__global__ __launch_bounds__(256) void ff1_fused_kernel(
    const bf16* __restrict__ A, const bf16* __restrict__ Bt,
    const float* __restrict__ bias, bf16* __restrict__ out, int K) {
  constexpr int BM = 128, ROWS = 384, ISS = 6;
  __shared__ __align__(16) bf16 sAB[2][ROWS][32];

  int wid = threadIdx.x >> 6, lane = threadIdx.x & 63;
  int row0 = blockIdx.y * BM, col0 = blockIdx.x * 128;
  int wr = (wid >> 1) * 64;
  int wc = (wid & 1) * 64;
  int lr = lane >> 2;
  int lc = (lane & 3) * 8;

  f32x4 acc1[4][4], acc2[4][4];
#pragma unroll
  for (int m = 0; m < 4; m++)
#pragma unroll
    for (int n = 0; n < 4; n++) {
      acc1[m][n] = (f32x4){0.f, 0.f, 0.f, 0.f};
      acc2[m][n] = (f32x4){0.f, 0.f, 0.f, 0.f};
    }

  auto stage = [&](int buf, int k0) {
#pragma unroll
    for (int i = 0; i < ISS; i++) {
      int rb = (wid * ISS + i) * 16;
      int r = rb + lr;
      const bf16* src;
      if (r < BM)       src = A  + (size_t)(row0 + r) * K + k0 + lc;
      else if (r < 256) src = Bt + (size_t)(col0 + (r - 128)) * K + k0 + lc;
      else              src = Bt + (size_t)(1024 + col0 + (r - 256)) * K + k0 + lc;
      __builtin_amdgcn_global_load_lds(
          (const __attribute__((address_space(1))) void*)src,
          (__attribute__((address_space(3))) void*)&sAB[buf][rb][0], 16, 0, 0);
    }
  };

  stage(0, 0);
  asm volatile("s_waitcnt vmcnt(0)" ::: "memory");
  __syncthreads();

  int cur = 0;
  for (int k0 = 0; k0 < K; k0 += 32, cur ^= 1) {
    if (k0 + 32 < K) stage(cur ^ 1, k0 + 32);
    short8 a[4], b1[4], b2[4];
    int kk = (lane >> 4) * 8;
#pragma unroll
    for (int m = 0; m < 4; m++)
      a[m] = *(const short8*)&sAB[cur][wr + m * 16 + (lane & 15)][kk];
#pragma unroll
    for (int n = 0; n < 4; n++) {
      b1[n] = *(const short8*)&sAB[cur][128 + wc + n * 16 + (lane & 15)][kk];
      b2[n] = *(const short8*)&sAB[cur][256 + wc + n * 16 + (lane & 15)][kk];
    }
#pragma unroll
    for (int m = 0; m < 4; m++)
#pragma unroll
      for (int n = 0; n < 4; n++) {
        acc1[m][n] = __builtin_amdgcn_mfma_f32_16x16x32_bf16(a[m], b1[n], acc1[m][n], 0, 0, 0);
        acc2[m][n] = __builtin_amdgcn_mfma_f32_16x16x32_bf16(a[m], b2[n], acc2[m][n], 0, 0, 0);
      }
    asm volatile("s_waitcnt vmcnt(0)" ::: "memory");
    __syncthreads();
  }

  int crow = row0 + wr + (lane >> 4) * 4;
  int ccol = col0 + wc + (lane & 15);
#pragma unroll
  for (int m = 0; m < 4; m++) {
#pragma unroll
    for (int n = 0; n < 4; n++) {
      int colg = ccol + n * 16;
      float bv1 = bias[colg];
      float bv2 = bias[1024 + colg];
#pragma unroll
      for (int j = 0; j < 4; j++) {
        int rowg = crow + m * 16 + j;
        float f1 = acc1[m][n][j] + bv1;
        float g  = acc2[m][n][j] + bv2;
        float sg = g / (1.f + expf(-g));
        out[(size_t)rowg * 1024 + colg] = __float2bfloat16(f1 * sg);
      }
    }
  }
}

// ---------------- tree scan: bf16-packed transport (8 bpermute + 4 b128) ----
// lane = (w, q): w = lane>>2, pl = wid*4 + q. State h[16] fp32 in VGPRs;
// cross-w transport packs 2 states per bpermute word (bf16).
__global__ __launch_bounds__(256) void tree_scan_kernel(
    const bf16* __restrict__ xb, const float* __restrict__ aux,
    const int* __restrict__ parent,
    const float* __restrict__ A_log, const float* __restrict__ dt_bias,
    const float* __restrict__ Dp, bf16* __restrict__ y) {
  const int tid = threadIdx.x;
  const int ps = blockIdx.x & 3;
  const int h  = (blockIdx.x >> 2) & 15;
  const int b  = blockIdx.x >> 6;
  const int wid = tid >> 6;
  const int lane = tid & 63;
  const int w = lane >> 2;
  const int q = lane & 3;
  const int pl = wid * 4 + q;

  // BCs[t][w]: u32 words [0:8)=B (bf16 pairs), [8:16)=C; stride 20 (80B)
  __shared__ __align__(16) u32   BCs[8][16][20];
  __shared__ __align__(16) float dAs[16][8];
  __shared__ __align__(16) float dtss[16][8];
  __shared__ __align__(16) int   pars[16][8];

  const float Ah  = -expf(A_log[h]);
  const float dtb = dt_bias[h];
  const float Dh  = Dp[h];
  const int xcol = 1024 + (h << 6) + (ps << 4) + pl;
  const int ycol = (h << 6) + (ps << 4) + pl;

  float hst[16];
#pragma unroll
  for (int n = 0; n < 16; n++) hst[n] = 0.f;

  // staging indices: pair = tid>>1 -> (t = pair>>4, w = pair&15), half = tid&1
  const int sp_t = (tid >> 1) >> 4, sp_w = (tid >> 1) & 15, sp_h = tid & 1;

  for (int c = 0; c < 8; c++) {
    const int t0 = c * 8;
    __syncthreads();  // previous chunk's compute done
    // x prefetch: 8 bf16 global loads for this lane's (w, pl)
    float xv[8];
#pragma unroll
    for (int tt = 0; tt < 8; tt++) {
      size_t row = ((size_t)(b * NT + t0 + tt)) * NW + w;
      xv[tt] = __bfloat162float(xb[row * PROJ_LD + xcol]);
    }
    // stage dt / dA / parent
    if (tid < 128) {
      int t = tid >> 4, wv = tid & 15;
      size_t row = ((size_t)(b * NT + t0 + t)) * NW + wv;
      float dtr = aux[row * 64 + 32 + h] + dtb;
      float dtv = (dtr > 20.f) ? dtr : log1pf(expf(dtr));
      dtss[wv][t] = dtv;
      dAs[wv][t]  = expf(dtv * Ah);
      pars[wv][t] = parent[row];
    }
    // stage B or C (16 floats -> 8 packed words) per (t,w,half)
    {
      size_t row = ((size_t)(b * NT + t0 + sp_t)) * NW + sp_w;
      const float* src = aux + row * 64 + sp_h * 16;
      float4 v0 = *(const float4*)&src[0];
      float4 v1 = *(const float4*)&src[4];
      float4 v2 = *(const float4*)&src[8];
      float4 v3 = *(const float4*)&src[12];
      uint4 p0 = {pack_bf(v0.x, v0.y), pack_bf(v0.z, v0.w),
                  pack_bf(v1.x, v1.y), pack_bf(v1.z, v1.w)};
      uint4 p1 = {pack_bf(v2.x, v2.y), pack_bf(v2.z, v2.w),
                  pack_bf(v3.x, v3.y), pack_bf(v3.z, v3.w)};
      *(uint4*)&BCs[sp_t][sp_w][sp_h * 8]     = p0;
      *(uint4*)&BCs[sp_t][sp_w][sp_h * 8 + 4] = p1;
    }
    __syncthreads();
    // reg-pack per-lane (w) params
    float dAr[8], dtr8[8];
    int parr[8];
    *(float4*)&dAr[0]  = *(const float4*)&dAs[w][0];
    *(float4*)&dAr[4]  = *(const float4*)&dAs[w][4];
    *(float4*)&dtr8[0] = *(const float4*)&dtss[w][0];
    *(float4*)&dtr8[4] = *(const float4*)&dtss[w][4];
    *(int4*)&parr[0]   = *(const int4*)&pars[w][0];
    *(int4*)&parr[4]   = *(const int4*)&pars[w][4];

#pragma unroll
    for (int tt = 0; tt < 8; tt++) {
      float dA  = dAr[tt];
      float dtx = dtr8[tt] * xv[tt];
      int   par = parr[tt];
      int gidx = (((par << 2) | q) << 2);
      // pack state pairs to bf16, gather via 8 bpermutes
      u32 pk[8];
#pragma unroll
      for (int i = 0; i < 8; i++)
        pk[i] = (u32)__builtin_amdgcn_ds_bpermute(
            gidx, (int)pack_bf(hst[2 * i], hst[2 * i + 1]));
      // B/C packed rows (broadcast within quad)
      uint4 bA = *(const uint4*)&BCs[tt][w][0];
      uint4 bB = *(const uint4*)&BCs[tt][w][4];
      uint4 cA = *(const uint4*)&BCs[tt][w][8];
      uint4 cB = *(const uint4*)&BCs[tt][w][12];
      const u32* bw = (const u32*)&bA;  // bA,bB adjacent? use explicit arrays
      u32 bwv[8] = {bA.x, bA.y, bA.z, bA.w, bB.x, bB.y, bB.z, bB.w};
      u32 cwv[8] = {cA.x, cA.y, cA.z, cA.w, cB.x, cB.y, cB.z, cB.w};
      (void)bw;
      float yv = 0.f;
#pragma unroll
      for (int i = 0; i < 8; i++) {
        u32 g = pk[i], bu = bwv[i], cu = cwv[i];
        float hp0 = ubits(g << 16),  hp1 = ubits(g & 0xffff0000u);
        float bl  = ubits(bu << 16), bh  = ubits(bu & 0xffff0000u);
        float cl  = ubits(cu << 16), ch  = ubits(cu & 0xffff0000u);
        float h0 = fmaf(dA, hp0, dtx * bl);
        float h1 = fmaf(dA, hp1, dtx * bh);
        hst[2 * i] = h0;
        hst[2 * i + 1] = h1;
        yv = fmaf(h0, cl, fmaf(h1, ch, yv));
      }
      size_t row = ((size_t)(b * NT + t0 + tt)) * NW + w;
      y[row * D_INNER + ycol] = __float2bfloat16(fmaf(Dh, xv[tt], yv));
    }
  }
}

// ---------------- gated RMSNorm (bf16 in/out) -------------------------------
__global__ __launch_bounds__(256) void gate_rms_kernel(
    const bf16* __restrict__ yin, const bf16* __restrict__ projb,
    const float* __restrict__ norm_w, bf16* __restrict__ out) {
  __shared__ float sbuf[8];
  int row = blockIdx.x;
  const bf16* yr = yin + (size_t)row * D_INNER;
  const bf16* zr = projb + (size_t)row * PROJ_LD;  // z = cols [0,1024)
  int c = threadIdx.x * 4;
  bf16 y4[4], z4[4];
  *(uint2*)y4 = *(const uint2*)&yr[c];
  *(uint2*)z4 = *(const uint2*)&zr[c];
  float gv[4];
  float ss = 0.f;
#pragma unroll
  for (int j = 0; j < 4; j++) {
    float z = __bfloat162float(z4[j]);
    float t = __bfloat162float(y4[j]) * (z / (1.f + expf(-z)));
    gv[j] = t;
    ss += t * t;
  }
  ss = block_sum(ss, sbuf);
  float scale = rsqrtf(ss * (1.f / 1024.f) + 1e-5f);
  bf16 o4[4];
#pragma unroll
  for (int j = 0; j < 4; j++) o4[j] = __float2bfloat16(gv[j] * scale * norm_w[c + j]);
  *(uint2*)&out[(size_t)row * D_INNER + c] = *(uint2*)o4;
}

extern "C" void kernel_launch(void* const* d_in, const int* in_sizes, int n_in,
                              void* d_out, int out_size, void* d_ws, size_t ws_size,
                              hipStream_t stream) {
  const float* x       = (const float*)d_in[0];
  const int*   parent  = (const int*)d_in[1];
  const float* ln1_w   = (const float*)d_in[2];
  const float* ln1_b   = (const float*)d_in[3];
  const float* in_w    = (const float*)d_in[4];
  const float* in_b    = (const float*)d_in[5];
  const float* A_log   = (const float*)d_in[6];
  const float* dt_bias = (const float*)d_in[7];
  const float* Dp      = (const float*)d_in[8];
  const float* norm_w  = (const float*)d_in[9];
  const float* out_w   = (const float*)d_in[10];
  const float* out_b   = (const float*)d_in[11];
  const float* ln2_w   = (const float*)d_in[12];
  const float* ln2_b   = (const float*)d_in[13];
  const float* ff1_w   = (const float*)d_in[14];
  const float* ff1_b   = (const float*)d_in[15];
  const float* ff2_w   = (const float*)d_in[16];
  const float* ff2_b   = (const float*)d_in[17];
  float* outp = (float*)d_out;

  char* wp = (char*)d_ws;
  bf16* xnb    = (bf16*)wp;  wp += (size_t)MROWS * D_MODEL * 2;
  bf16* in_wt  = (bf16*)wp;  wp += (size_t)PROJ_LD * D_MODEL * 2;
  bf16* out_wt = (bf16*)wp;  wp += (size_t)D_MODEL * D_INNER * 2;
  bf16* ff1_wt = (bf16*)wp;  wp += (size_t)2048 * D_MODEL * 2;
  bf16* ff2_wt = (bf16*)wp;  wp += (size_t)D_MODEL * D_INNER * 2;
  bf16* projb  = (bf16*)wp;  wp += (size_t)MROWS * PROJ_LD * 2;
  float* aux   = (float*)wp; wp += (size_t)MROWS * 64 * 4;
  bf16* yb     = (bf16*)wp;  wp += (size_t)MROWS * D_INNER * 2;
  bf16* ygb    = (bf16*)wp;  wp += (size_t)MROWS * D_INNER * 2;
  float* xmid  = outp;  // d_out doubles as xmid

  dim3 blk(256);
  wconv_t_kernel<<<dim3(PROJ_LD / 32, D_MODEL / 32), blk, 0, stream>>>(
      in_w, in_wt, D_MODEL, NPROJ, PROJ_LD);
  wconv_t_kernel<<<dim3(D_MODEL / 32, D_INNER / 32), blk, 0, stream>>>(
      out_w, out_wt, D_INNER, D_MODEL, D_MODEL);
  wconv_t_kernel<<<dim3(2048 / 32, D_MODEL / 32), blk, 0, stream>>>(
      ff1_w, ff1_wt, D_MODEL, 2048, 2048);
  wconv_t_kernel<<<dim3(D_MODEL / 32, D_INNER / 32), blk, 0, stream>>>(
      ff2_w, ff2_wt, D_INNER, D_MODEL, D_MODEL);

  // 1) LN1 -> bf16
  ln512_bf16_kernel<<<MROWS, blk, 0, stream>>>(x, ln1_w, ln1_b, xnb);
  // 2) in-proj GEMM -> projb (bf16) + aux (fp32 B/C/dt)
  inproj_gemm_kernel<<<dim3(PROJ_LD / 128, MROWS / 128), blk, 0, stream>>>(
      xnb, in_wt, in_b, projb, aux, D_MODEL);
  // 3) tree scan -> yb (bf16)
  tree_scan_kernel<<<NB * NHEAD * 4, blk, 0, stream>>>(projb, aux, parent,
                                                       A_log, dt_bias, Dp, yb);
  // 4) gated RMSNorm -> ygb (bf16)
  gate_rms_kernel<<<MROWS, blk, 0, stream>>>(yb, projb, norm_w, ygb);
  // 5) out-proj GEMM + resid(x) -> xmid (fp32)
  mfma_gemm_kernel<64, 128, 4, 4, 2><<<dim3(D_MODEL / 128, MROWS / 64), blk, 0, stream>>>(
      ygb, out_wt, out_b, D_MODEL, x, xmid, D_MODEL, D_INNER);
  // 6) LN2 -> xnb
  ln512_bf16_kernel<<<MROWS, blk, 0, stream>>>(xmid, ln2_w, ln2_b, xnb);
  // 7) FF1 GEMM + SiLU gate fused -> ygb (bf16, reuse)
  ff1_fused_kernel<<<dim3(8, MROWS / 128), blk, 0, stream>>>(
      xnb, ff1_wt, ff1_b, ygb, D_MODEL);
  // 8) FF2 GEMM + resid(xmid) -> d_out
  mfma_gemm_kernel<64, 128, 4, 4, 2><<<dim3(D_MODEL / 128, MROWS / 64), blk, 0, stream>>>(
      ygb, ff2_wt, ff2_b, D_MODEL, xmid, outp, D_MODEL, D_INNER);
}